// Round 2
// baseline (449.892 us; speedup 1.0000x reference)
//
#include <hip/hip_runtime.h>
#include <hip/hip_bf16.h>

typedef __bf16 bf16x8 __attribute__((ext_vector_type(8)));
typedef float  f32x4  __attribute__((ext_vector_type(4)));

#define B_   4
#define N_   4096
#define FIN  300
#define FOUT 300
#define FP   320   // padded feature / K dim (multiple of 32)

// ws layout (bytes)
#define WT_OFF   0                    // Wt   bf16 [FP][FP]
#define D_OFF    (512*1024)           // d    fp32 [B_*N_]
#define TSC_OFF  (1024*1024)          // Tsc  bf16 [B_*N_][FP]   (~10.5 MB)
#define YT_OFF   (16*1024*1024)       // Yt   bf16 [B_][FP][N_]  (~10.5 MB)
#define ADJB_OFF (32*1024*1024)       // adjb bf16 [B_][N_][N_]  (~134 MB)
#define ADJB_BYTES ((size_t)B_ * N_ * N_ * 2)

// ---------------- K0: Wt[f][k] = bf16(W[k][f]), zero-padded ----------------
__global__ void k_wt(const float* __restrict__ W, __bf16* __restrict__ Wt) {
    int t = blockIdx.x * 256 + threadIdx.x;
    if (t >= FP * FP) return;
    int f = t / FP, k = t - f * FP;
    float v = (f < FOUT && k < FIN) ? W[k * FOUT + f] : 0.0f;
    Wt[t] = (__bf16)v;
}

// ---------------- K1a: rowsum only (fallback path) -------------------------
__global__ void k_rowsum(const float* __restrict__ adj, float* __restrict__ d) {
    int row  = blockIdx.x * 4 + (threadIdx.x >> 6);
    int lane = threadIdx.x & 63;
    const float4* p = (const float4*)(adj + (size_t)row * N_);
    float s = 0.0f;
#pragma unroll
    for (int it = 0; it < 16; ++it) {
        float4 v = p[it * 64 + lane];
        s += v.x + v.y + v.z + v.w;
    }
#pragma unroll
    for (int off = 32; off; off >>= 1) s += __shfl_xor(s, off);
    if (lane == 0) d[row] = rsqrtf(s + 1.0f);
}

// ---------------- K1b: rowsum + bf16 conversion of adj (fused) -------------
__global__ void k_rowsum_cvt(const float* __restrict__ adj, float* __restrict__ d,
                             __bf16* __restrict__ adjb) {
    int row  = blockIdx.x * 4 + (threadIdx.x >> 6);
    int lane = threadIdx.x & 63;
    const float4* p = (const float4*)(adj + (size_t)row * N_);
    __bf16* q = adjb + (size_t)row * N_;
    float s = 0.0f;
#pragma unroll
    for (int it = 0; it < 8; ++it) {
        int idx = it * 128 + lane * 2;           // float4 index, even -> 16B aligned store
        float4 v0 = p[idx], v1 = p[idx + 1];
        s += v0.x + v0.y + v0.z + v0.w + v1.x + v1.y + v1.z + v1.w;
        bf16x8 o;
        o[0] = (__bf16)v0.x; o[1] = (__bf16)v0.y; o[2] = (__bf16)v0.z; o[3] = (__bf16)v0.w;
        o[4] = (__bf16)v1.x; o[5] = (__bf16)v1.y; o[6] = (__bf16)v1.z; o[7] = (__bf16)v1.w;
        *(bf16x8*)(q + idx * 4) = o;
    }
#pragma unroll
    for (int off = 32; off; off >>= 1) s += __shfl_xor(s, off);
    if (lane == 0) d[row] = rsqrtf(s + 1.0f);
}

// ---------------- K2: Tsc[j][k] = bf16(d[j]*text[j][k]), K zero-padded -----
__global__ void k_tsc(const float* __restrict__ text, const float* __restrict__ d,
                      __bf16* __restrict__ Tsc) {
    int t = blockIdx.x * 256 + threadIdx.x;
    int j = t / FP;
    int k = t - j * FP;
    float v = 0.0f;
    if (k < FIN) v = d[j] * text[(size_t)j * FIN + k];
    Tsc[t] = (__bf16)v;
}

// ---------------- K3: Yt[b][f][j] = sum_k Wt[f][k]*Tsc[b,j][k] -------------
__global__ __launch_bounds__(256) void k_y(const __bf16* __restrict__ Wt,
                                           const __bf16* __restrict__ Tsc,
                                           __bf16* __restrict__ Yt) {
    int b    = blockIdx.y;
    int j0   = blockIdx.x * 64;
    int wave = threadIdx.x >> 6, lane = threadIdx.x & 63;
    int lr = lane & 15, lg = lane >> 4;
    f32x4 acc[5][4] = {};
    for (int k0 = 0; k0 < FP; k0 += 32) {
        bf16x8 a[5], bb[4];
#pragma unroll
        for (int fi = 0; fi < 5; ++fi) {
            int f = (wave * 5 + fi) * 16 + lr;
            a[fi] = *(const bf16x8*)(Wt + (size_t)f * FP + k0 + lg * 8);
        }
#pragma unroll
        for (int ji = 0; ji < 4; ++ji) {
            int j = j0 + ji * 16 + lr;
            bb[ji] = *(const bf16x8*)(Tsc + ((size_t)(b * N_ + j)) * FP + k0 + lg * 8);
        }
#pragma unroll
        for (int fi = 0; fi < 5; ++fi)
#pragma unroll
            for (int ji = 0; ji < 4; ++ji)
                acc[fi][ji] = __builtin_amdgcn_mfma_f32_16x16x32_bf16(a[fi], bb[ji], acc[fi][ji], 0, 0, 0);
    }
#pragma unroll
    for (int fi = 0; fi < 5; ++fi)
#pragma unroll
        for (int ji = 0; ji < 4; ++ji)
#pragma unroll
            for (int r = 0; r < 4; ++r) {
                int f = (wave * 5 + fi) * 16 + lg * 4 + r;
                int j = j0 + ji * 16 + lr;
                Yt[((size_t)b * FP + f) * N_ + j] = (__bf16)acc[fi][ji][r];
            }
}

// ---------------- K4: out[b][i][f] = d_i * (adj @ Yt) + bias ---------------
// Block = 256 thr = 4 waves, each wave: 16 rows x 80 f-cols (5 n-tiles).
// Grid = (N_/16, B_) = 1024 blocks -> 4 blocks/CU, 3 waves/SIMD resident.
// 4-stage software pipeline over K (32 K per stage), named stage registers.
template<bool ABF16>
__global__ __launch_bounds__(256, 3) void k_gemm(const void* __restrict__ Aop,
                                                 const __bf16* __restrict__ Yt,
                                                 const float* __restrict__ d,
                                                 const float* __restrict__ bias,
                                                 float* __restrict__ out) {
    int b    = blockIdx.y;
    int wave = threadIdx.x >> 6, lane = threadIdx.x & 63;
    int lr = lane & 15, lg = lane >> 4;
    int rowbase = blockIdx.x * 16;
    int fbase   = wave * 80;

    const __bf16* aptr  = nullptr;
    const float*  afptr = nullptr;
    if constexpr (ABF16)
        aptr = (const __bf16*)Aop + ((size_t)b * N_ + rowbase + lr) * N_ + lg * 8;
    else
        afptr = (const float*)Aop + ((size_t)b * N_ + rowbase + lr) * N_ + lg * 8;

    const __bf16* bptr[5];
#pragma unroll
    for (int nt = 0; nt < 5; ++nt)
        bptr[nt] = Yt + ((size_t)b * FP + fbase + nt * 16 + lr) * N_ + lg * 8;

    f32x4 acc[5] = {};
    bf16x8 A0, A1, A2, A3;
    bf16x8 Bv0[5], Bv1[5], Bv2[5], Bv3[5];

#define LOADA(As, kk)                                                                  \
    {                                                                                  \
        if constexpr (ABF16) {                                                         \
            As = *(const bf16x8*)(aptr + (kk));                                        \
        } else {                                                                       \
            float4 v0 = *(const float4*)(afptr + (kk));                                \
            float4 v1 = *(const float4*)(afptr + (kk) + 4);                            \
            As[0] = (__bf16)v0.x; As[1] = (__bf16)v0.y;                                \
            As[2] = (__bf16)v0.z; As[3] = (__bf16)v0.w;                                \
            As[4] = (__bf16)v1.x; As[5] = (__bf16)v1.y;                                \
            As[6] = (__bf16)v1.z; As[7] = (__bf16)v1.w;                                \
        }                                                                              \
    }
#define LOADB(Bs, kk)                                                                  \
    {                                                                                  \
        _Pragma("unroll")                                                              \
        for (int nt = 0; nt < 5; ++nt) Bs[nt] = *(const bf16x8*)(bptr[nt] + (kk));     \
    }
#define MFMAST(As, Bs)                                                                 \
    {                                                                                  \
        _Pragma("unroll")                                                              \
        for (int nt = 0; nt < 5; ++nt)                                                 \
            acc[nt] = __builtin_amdgcn_mfma_f32_16x16x32_bf16(As, Bs[nt], acc[nt], 0, 0, 0); \
    }

    LOADA(A0, 0)   LOADB(Bv0, 0)
    LOADA(A1, 32)  LOADB(Bv1, 32)
    LOADA(A2, 64)  LOADB(Bv2, 64)
    LOADA(A3, 96)  LOADB(Bv3, 96)
    for (int k0 = 0; k0 < N_ - 128; k0 += 128) {
        MFMAST(A0, Bv0) LOADA(A0, k0 + 128) LOADB(Bv0, k0 + 128)
        MFMAST(A1, Bv1) LOADA(A1, k0 + 160) LOADB(Bv1, k0 + 160)
        MFMAST(A2, Bv2) LOADA(A2, k0 + 192) LOADB(Bv2, k0 + 192)
        MFMAST(A3, Bv3) LOADA(A3, k0 + 224) LOADB(Bv3, k0 + 224)
    }
    MFMAST(A0, Bv0) MFMAST(A1, Bv1) MFMAST(A2, Bv2) MFMAST(A3, Bv3)

    // epilogue: scale by d_i, add bias, store (f < 300 only)
    float di[4];
#pragma unroll
    for (int r = 0; r < 4; ++r)
        di[r] = d[b * N_ + rowbase + lg * 4 + r];
#pragma unroll
    for (int nt = 0; nt < 5; ++nt) {
        int f = fbase + nt * 16 + lr;
        if (f < FOUT) {
            float bv = bias[f];
#pragma unroll
            for (int r = 0; r < 4; ++r) {
                int i = rowbase + lg * 4 + r;
                out[((size_t)b * N_ + i) * FOUT + f] = di[r] * acc[nt][r] + bv;
            }
        }
    }
}

extern "C" void kernel_launch(void* const* d_in, const int* in_sizes, int n_in,
                              void* d_out, int out_size, void* d_ws, size_t ws_size,
                              hipStream_t stream) {
    const float* text = (const float*)d_in[0];
    const float* adj  = (const float*)d_in[1];
    const float* W    = (const float*)d_in[2];
    const float* bias = (const float*)d_in[3];
    float* out = (float*)d_out;

    char* ws = (char*)d_ws;
    __bf16* Wt   = (__bf16*)(ws + WT_OFF);
    float*  dv   = (float*)(ws + D_OFF);
    __bf16* Tsc  = (__bf16*)(ws + TSC_OFF);
    __bf16* Yt   = (__bf16*)(ws + YT_OFF);
    __bf16* adjb = (__bf16*)(ws + ADJB_OFF);

    bool big = ws_size >= (size_t)ADJB_OFF + ADJB_BYTES;

    k_wt<<<dim3((FP * FP + 255) / 256), dim3(256), 0, stream>>>(W, Wt);
    if (big)
        k_rowsum_cvt<<<dim3(B_ * N_ / 4), dim3(256), 0, stream>>>(adj, dv, adjb);
    else
        k_rowsum<<<dim3(B_ * N_ / 4), dim3(256), 0, stream>>>(adj, dv);
    k_tsc<<<dim3(B_ * N_ * FP / 256), dim3(256), 0, stream>>>(text, dv, Tsc);
    k_y<<<dim3(N_ / 64, B_), dim3(256), 0, stream>>>(Wt, Tsc, Yt);
    if (big)
        k_gemm<true><<<dim3(N_ / 16, B_), dim3(256), 0, stream>>>(adjb, Yt, dv, bias, out);
    else
        k_gemm<false><<<dim3(N_ / 16, B_), dim3(256), 0, stream>>>(adj, Yt, dv, bias, out);
}

// Round 3
// 303.075 us; speedup vs baseline: 1.4844x; 1.4844x over previous
//
#include <hip/hip_runtime.h>
#include <hip/hip_bf16.h>

typedef __bf16 bf16x8 __attribute__((ext_vector_type(8)));
typedef float  f32x4  __attribute__((ext_vector_type(4)));

#define B_   4
#define N_   4096
#define FIN  300
#define FOUT 300
#define FP   320   // padded feature dim (multiple of 32)
#define MT   64    // A m-tile rows
#define KT   64    // A k-tile cols
#define NMT  (N_/MT)
#define NKT  (N_/KT)
#define TILE_BYTES (MT*KT*2)   // 8192

// ws layout (bytes)
#define WT_OFF   0                    // Wt   bf16 [FP][FP]
#define D_OFF    (512*1024)           // d    fp32 [B_*N_]
#define TSC_OFF  (1024*1024)          // Tsc  bf16 [B_*N_][FP]
#define YT_OFF   (16*1024*1024)       // Yt   bf16 [B_][FP][N_]
#define ADJB_OFF (32*1024*1024)       // adjb bf16 tiled+swizzled [B_][NMT][NKT][8KB]
#define ADJB_BYTES ((size_t)B_ * N_ * N_ * 2)

__device__ __forceinline__ void gload_lds16(const void* g, void* l) {
    __builtin_amdgcn_global_load_lds((const __attribute__((address_space(1))) void*)g,
                                     (__attribute__((address_space(3))) void*)l, 16, 0, 0);
}

// ---------------- K0: Wt[f][k] = bf16(W[k][f]), zero-padded ----------------
__global__ void k_wt(const float* __restrict__ W, __bf16* __restrict__ Wt) {
    int t = blockIdx.x * 256 + threadIdx.x;
    if (t >= FP * FP) return;
    int f = t / FP, k = t - f * FP;
    float v = (f < FOUT && k < FIN) ? W[k * FOUT + f] : 0.0f;
    Wt[t] = (__bf16)v;
}

// ---------------- K1a: rowsum only (fallback path) -------------------------
__global__ void k_rowsum(const float* __restrict__ adj, float* __restrict__ d) {
    int row  = blockIdx.x * 4 + (threadIdx.x >> 6);
    int lane = threadIdx.x & 63;
    const float4* p = (const float4*)(adj + (size_t)row * N_);
    float s = 0.0f;
#pragma unroll
    for (int it = 0; it < 16; ++it) {
        float4 v = p[it * 64 + lane];
        s += v.x + v.y + v.z + v.w;
    }
#pragma unroll
    for (int off = 32; off; off >>= 1) s += __shfl_xor(s, off);
    if (lane == 0) d[row] = rsqrtf(s + 1.0f);
}

// ---------------- K1b: rowsum + tiled/swizzled bf16 copy of adj ------------
// One wave per row; lane owns one 64-elem k-tile of that row.
// Tile layout: adjb[(b*NMT+mt)*NKT + kt] is 8 KB = rows [mloc][64 bf16],
// with 16B chunk c stored at byte  mloc*128 + (c*16 ^ ((mloc&7)<<4)).
__global__ void k_rowsum_cvt(const float* __restrict__ adj, float* __restrict__ d,
                             char* __restrict__ adjb) {
    int g    = blockIdx.x * 4 + (threadIdx.x >> 6);   // global row 0..B_*N_-1
    int lane = threadIdx.x & 63;                      // = kt
    int b    = g >> 12;
    int row  = g & (N_ - 1);
    int mt   = row >> 6, mloc = row & 63;
    const float4* p = (const float4*)(adj + (size_t)g * N_) + lane * 16;
    float4 v[16];
#pragma unroll
    for (int i = 0; i < 16; ++i) v[i] = p[i];
    float s = 0.0f;
#pragma unroll
    for (int i = 0; i < 16; ++i) s += v[i].x + v[i].y + v[i].z + v[i].w;
    char* tb = adjb + (size_t)((b * NMT + mt) * NKT + lane) * TILE_BYTES + mloc * 128;
    int sw = (mloc & 7) << 4;
#pragma unroll
    for (int c = 0; c < 8; ++c) {
        float4 v0 = v[2 * c], v1 = v[2 * c + 1];
        bf16x8 o;
        o[0] = (__bf16)v0.x; o[1] = (__bf16)v0.y; o[2] = (__bf16)v0.z; o[3] = (__bf16)v0.w;
        o[4] = (__bf16)v1.x; o[5] = (__bf16)v1.y; o[6] = (__bf16)v1.z; o[7] = (__bf16)v1.w;
        *(bf16x8*)(tb + ((c * 16) ^ sw)) = o;
    }
#pragma unroll
    for (int off = 32; off; off >>= 1) s += __shfl_xor(s, off);
    if (lane == 0) d[g] = rsqrtf(s + 1.0f);
}

// ---------------- K2: Tsc[j][k] = bf16(d[j]*text[j][k]), K zero-padded -----
__global__ void k_tsc(const float* __restrict__ text, const float* __restrict__ d,
                      __bf16* __restrict__ Tsc) {
    int t = blockIdx.x * 256 + threadIdx.x;
    int j = t / FP;
    int k = t - j * FP;
    float v = 0.0f;
    if (k < FIN) v = d[j] * text[(size_t)j * FIN + k];
    Tsc[t] = (__bf16)v;
}

// ---------------- K3: Yt[b][f][j] = sum_k Wt[f][k]*Tsc[b,j][k] -------------
__global__ __launch_bounds__(256) void k_y(const __bf16* __restrict__ Wt,
                                           const __bf16* __restrict__ Tsc,
                                           __bf16* __restrict__ Yt) {
    int b    = blockIdx.y;
    int j0   = blockIdx.x * 64;
    int wave = threadIdx.x >> 6, lane = threadIdx.x & 63;
    int lr = lane & 15, lg = lane >> 4;
    f32x4 acc[5][4] = {};
    for (int k0 = 0; k0 < FP; k0 += 32) {
        bf16x8 a[5], bb[4];
#pragma unroll
        for (int fi = 0; fi < 5; ++fi) {
            int f = (wave * 5 + fi) * 16 + lr;
            a[fi] = *(const bf16x8*)(Wt + (size_t)f * FP + k0 + lg * 8);
        }
#pragma unroll
        for (int ji = 0; ji < 4; ++ji) {
            int j = j0 + ji * 16 + lr;
            bb[ji] = *(const bf16x8*)(Tsc + ((size_t)(b * N_ + j)) * FP + k0 + lg * 8);
        }
#pragma unroll
        for (int fi = 0; fi < 5; ++fi)
#pragma unroll
            for (int ji = 0; ji < 4; ++ji)
                acc[fi][ji] = __builtin_amdgcn_mfma_f32_16x16x32_bf16(a[fi], bb[ji], acc[fi][ji], 0, 0, 0);
    }
#pragma unroll
    for (int fi = 0; fi < 5; ++fi)
#pragma unroll
        for (int ji = 0; ji < 4; ++ji)
#pragma unroll
            for (int r = 0; r < 4; ++r) {
                int f = (wave * 5 + fi) * 16 + lg * 4 + r;
                int j = j0 + ji * 16 + lr;
                Yt[((size_t)b * FP + f) * N_ + j] = (__bf16)acc[fi][ji][r];
            }
}

// ---------------- K4: out[b][i][f] = d_i * (adj @ Yt) + bias ---------------
// BM=64, BN=160, BK=64. 4 waves = 2m x 2n, wave tile 32x80 (2x5 frags).
// A: global_load_lds -> double-buffered LDS (pre-swizzled tiles, linear copy).
// B: direct global (L2-resident Yt), 1 tile ahead in named register sets.
__global__ __launch_bounds__(256) void k_gemm_bf16(const char* __restrict__ adjb,
                                                   const __bf16* __restrict__ Yt,
                                                   const float* __restrict__ d,
                                                   const float* __restrict__ bias,
                                                   float* __restrict__ out) {
    __shared__ __align__(16) char smem[2 * TILE_BYTES];
    const int b = blockIdx.z, bx = blockIdx.x, by = blockIdx.y;
    const int w = threadIdx.x >> 6, lane = threadIdx.x & 63;
    const int wm = w & 1, wn = w >> 1;
    const int lr = lane & 15, lg = lane >> 4;

    const char* atile = adjb + (size_t)((b * NMT + bx) * NKT) * TILE_BYTES;
    const int sgo = w * 2048 + lane * 16;   // per-thread share of an 8 KB tile (2x16B)

    const __bf16* bp[5];
#pragma unroll
    for (int nt = 0; nt < 5; ++nt)
        bp[nt] = Yt + ((size_t)b * FP + by * 160 + wn * 80 + nt * 16 + lr) * N_ + lg * 8;

    // swizzled LDS byte offsets for the 4 A-frags (mi, kh)
    const int m0 = wm * 32 + lr, m1 = m0 + 16;      // m1&7 == m0&7
    const int sw = (m0 & 7) << 4;
    const int a00 = m0 * 128 + ((lg * 16) ^ sw);
    const int a01 = m0 * 128 + ((64 + lg * 16) ^ sw);
    const int a10 = m1 * 128 + ((lg * 16) ^ sw);
    const int a11 = m1 * 128 + ((64 + lg * 16) ^ sw);

    f32x4 acc[2][5] = {};
    bf16x8 BA[5][2], BB[5][2], Af[2][2];

#define STAGE_(bufofs, kt) { \
    const char* gs = atile + (size_t)(kt) * TILE_BYTES + sgo; \
    char* ls = smem + (bufofs) + w * 2048; \
    gload_lds16(gs, ls); \
    gload_lds16(gs + 1024, ls + 1024); }

#define LOADB_(S, kt) { _Pragma("unroll") \
    for (int nt = 0; nt < 5; ++nt) { \
        S[nt][0] = *(const bf16x8*)(bp[nt] + (kt) * 64); \
        S[nt][1] = *(const bf16x8*)(bp[nt] + (kt) * 64 + 32); } }

#define LDA_(bufofs) { \
    const char* base_ = smem + (bufofs); \
    Af[0][0] = *(const bf16x8*)(base_ + a00); \
    Af[0][1] = *(const bf16x8*)(base_ + a01); \
    Af[1][0] = *(const bf16x8*)(base_ + a10); \
    Af[1][1] = *(const bf16x8*)(base_ + a11); }

#define MM_(S) { _Pragma("unroll") \
    for (int kh = 0; kh < 2; ++kh) \
        _Pragma("unroll") \
        for (int mi = 0; mi < 2; ++mi) \
            _Pragma("unroll") \
            for (int nt = 0; nt < 5; ++nt) \
                acc[mi][nt] = __builtin_amdgcn_mfma_f32_16x16x32_bf16(Af[mi][kh], S[nt][kh], acc[mi][nt], 0, 0, 0); }

    STAGE_(0, 0)
    LOADB_(BA, 0)
    __syncthreads();
    for (int t = 0; t < NKT; t += 2) {
        STAGE_(TILE_BYTES, t + 1)       // issue next A-tile into buf1
        LOADB_(BB, t + 1)               // next B into alternate set
        LDA_(0)
        MM_(BA)
        __syncthreads();                // drains vmcnt -> tile t+1 ready
        if (t + 2 < NKT) { STAGE_(0, t + 2) LOADB_(BA, t + 2) }
        LDA_(TILE_BYTES)
        MM_(BB)
        __syncthreads();
    }

    // epilogue: scale by d_i, add bias, store (f < 300 only)
    const int rowb = bx * 64 + wm * 32;
    float di[2][4];
#pragma unroll
    for (int mi = 0; mi < 2; ++mi)
#pragma unroll
        for (int r = 0; r < 4; ++r)
            di[mi][r] = d[b * N_ + rowb + mi * 16 + lg * 4 + r];
#pragma unroll
    for (int nt = 0; nt < 5; ++nt) {
        int f = by * 160 + wn * 80 + nt * 16 + lr;
        if (f < FOUT) {
            float bv = bias[f];
#pragma unroll
            for (int mi = 0; mi < 2; ++mi)
#pragma unroll
                for (int r = 0; r < 4; ++r) {
                    int i = rowb + mi * 16 + lg * 4 + r;
                    out[((size_t)b * N_ + i) * FOUT + f] = di[mi][r] * acc[mi][nt][r] + bv;
                }
        }
    }
#undef STAGE_
#undef LOADB_
#undef LDA_
#undef MM_
}

// ---------------- Fallback GEMM (fp32 adj direct; only if ws too small) ----
#define FB_LOAD(AV, BV, K0)                                                           \
    {                                                                                 \
        _Pragma("unroll")                                                             \
        for (int mi = 0; mi < 2; ++mi) {                                              \
            const float4* p = (const float4*)(adjb + (size_t)(rowbase + mi * 16 + lr) * N_ + (K0) + lg * 8); \
            float4 v0 = p[0], v1 = p[1];                                              \
            AV[mi][0] = (__bf16)v0.x; AV[mi][1] = (__bf16)v0.y;                       \
            AV[mi][2] = (__bf16)v0.z; AV[mi][3] = (__bf16)v0.w;                       \
            AV[mi][4] = (__bf16)v1.x; AV[mi][5] = (__bf16)v1.y;                       \
            AV[mi][6] = (__bf16)v1.z; AV[mi][7] = (__bf16)v1.w;                       \
        }                                                                             \
        _Pragma("unroll")                                                             \
        for (int nt = 0; nt < 10; ++nt) {                                             \
            int f = wn * 160 + nt * 16 + lr;                                          \
            BV[nt] = *(const bf16x8*)(Yb + (size_t)f * N_ + (K0) + lg * 8);           \
        }                                                                             \
    }
#define FB_MFMA(AV, BV)                                                               \
    {                                                                                 \
        _Pragma("unroll")                                                             \
        for (int mi = 0; mi < 2; ++mi)                                                \
            _Pragma("unroll")                                                         \
            for (int nt = 0; nt < 10; ++nt)                                           \
                acc[mi][nt] = __builtin_amdgcn_mfma_f32_16x16x32_bf16(AV[mi], BV[nt], acc[mi][nt], 0, 0, 0); \
    }

__global__ __launch_bounds__(256) void k_gemm_fb(const float* __restrict__ adj,
                                                 const __bf16* __restrict__ Yt,
                                                 const float* __restrict__ d,
                                                 const float* __restrict__ bias,
                                                 float* __restrict__ out) {
    int b    = blockIdx.y;
    int wave = threadIdx.x >> 6, lane = threadIdx.x & 63;
    int wm = wave & 1, wn = wave >> 1;
    int lr = lane & 15, lg = lane >> 4;
    int rowbase = blockIdx.x * 64 + wm * 32;
    const float*  adjb = adj + (size_t)b * N_ * N_;
    const __bf16* Yb   = Yt + (size_t)b * FP * N_;

    f32x4 acc[2][10] = {};
    bf16x8 aA[2], bA[10], aB[2], bB[10];

    FB_LOAD(aA, bA, 0)
    for (int k0 = 0; k0 < N_ - 64; k0 += 64) {
        FB_LOAD(aB, bB, k0 + 32)
        FB_MFMA(aA, bA)
        FB_LOAD(aA, bA, k0 + 64)
        FB_MFMA(aB, bB)
    }
    FB_LOAD(aB, bB, N_ - 32)
    FB_MFMA(aA, bA)
    FB_MFMA(aB, bB)

#pragma unroll
    for (int mi = 0; mi < 2; ++mi) {
        float di[4];
#pragma unroll
        for (int r = 0; r < 4; ++r)
            di[r] = d[b * N_ + rowbase + mi * 16 + lg * 4 + r];
#pragma unroll
        for (int nt = 0; nt < 10; ++nt) {
            int f = wn * 160 + nt * 16 + lr;
            if (f < FOUT) {
                float bv = bias[f];
#pragma unroll
                for (int r = 0; r < 4; ++r) {
                    int i = rowbase + mi * 16 + lg * 4 + r;
                    out[((size_t)b * N_ + i) * FOUT + f] = di[r] * acc[mi][nt][r] + bv;
                }
            }
        }
    }
}

extern "C" void kernel_launch(void* const* d_in, const int* in_sizes, int n_in,
                              void* d_out, int out_size, void* d_ws, size_t ws_size,
                              hipStream_t stream) {
    const float* text = (const float*)d_in[0];
    const float* adj  = (const float*)d_in[1];
    const float* W    = (const float*)d_in[2];
    const float* bias = (const float*)d_in[3];
    float* out = (float*)d_out;

    char* ws = (char*)d_ws;
    __bf16* Wt   = (__bf16*)(ws + WT_OFF);
    float*  dv   = (float*)(ws + D_OFF);
    __bf16* Tsc  = (__bf16*)(ws + TSC_OFF);
    __bf16* Yt   = (__bf16*)(ws + YT_OFF);
    char*   adjb = ws + ADJB_OFF;

    bool big = ws_size >= (size_t)ADJB_OFF + ADJB_BYTES;

    k_wt<<<dim3((FP * FP + 255) / 256), dim3(256), 0, stream>>>(W, Wt);
    if (big)
        k_rowsum_cvt<<<dim3(B_ * N_ / 4), dim3(256), 0, stream>>>(adj, dv, adjb);
    else
        k_rowsum<<<dim3(B_ * N_ / 4), dim3(256), 0, stream>>>(adj, dv);
    k_tsc<<<dim3(B_ * N_ * FP / 256), dim3(256), 0, stream>>>(text, dv, Tsc);
    k_y<<<dim3(N_ / 64, B_), dim3(256), 0, stream>>>(Wt, Tsc, Yt);
    if (big)
        k_gemm_bf16<<<dim3(NMT, 2, B_), dim3(256), 0, stream>>>(adjb, Yt, dv, bias, out);
    else
        k_gemm_fb<<<dim3(N_ / 64, B_), dim3(256), 0, stream>>>(adj, Yt, dv, bias, out);
}